// Round 2
// baseline (211.379 us; speedup 1.0000x reference)
//
#include <hip/hip_runtime.h>
#include <hip/hip_bf16.h>

// MambaBlock: H=256, S=16, B=2, N=8192. fp32 I/O (per reference dtypes).
// No decay (A_log unused) => SSM state is a pure prefix-sum: chunk-parallel.
// GEMMs via bf16 MFMA (inputs converted); scan/LN math in fp32.

#define HD 256
#define SD 16
#define NSEQ 8192
#define NBATCH 2
#define BN (NBATCH * NSEQ)      // 16384 rows
#define CHUNK 32
#define NCHUNK (NSEQ / CHUNK)   // 256
#define NGRP 16                 // groups of 16 chunks for 2-level prefix
#define GSZ (NCHUNK / NGRP)     // 16
#define LN_EPS 1e-5f

#define NX  (BN * HD)           // 4,194,304  x elements
#define NIW (2 * HD * HD)       // 131,072    in_w
#define NXP (48 * HD)           // 12,288     xp_w padded (src 33*256=8448)
#define NOW (HD * HD)           // 65,536     out_w

typedef __hip_bfloat16 bf16;
typedef __attribute__((ext_vector_type(8))) short bf16x8;
typedef __attribute__((ext_vector_type(4))) short short4v;
typedef __attribute__((ext_vector_type(4))) float f32x4;

__device__ __forceinline__ short f2bs(float f) {
  union { bf16 b; short s; } u;
  u.b = __float2bfloat16(f);
  return u.s;
}

// Convert 8 contiguous fp32 -> bf16x8 fragment (compiler vectorizes the loads)
__device__ __forceinline__ bf16x8 cvt_frag(const float* __restrict__ p) {
  bf16x8 r;
#pragma unroll
  for (int j = 0; j < 8; ++j) r[j] = f2bs(p[j]);
  return r;
}

// ---------------------------------------------------------------------------
// K0: fp32 -> bf16 conversions: x->xb, in_w->wb_in, xp_w->wb_xp (zero-padded
// to 48 rows), out_w->wb_out. 4 elements/thread.
// ---------------------------------------------------------------------------
__global__ __launch_bounds__(256) void k0_convert(
    const float* __restrict__ x, const float* __restrict__ in_w,
    const float* __restrict__ xp_w, const float* __restrict__ out_w,
    bf16* __restrict__ xb, bf16* __restrict__ wb_in,
    bf16* __restrict__ wb_xp, bf16* __restrict__ wb_out)
{
  const int base = (blockIdx.x * 256 + threadIdx.x) * 4;
  if (base < NX) {
    f32x4 v = *(const f32x4*)(x + base);
    short4v s = {f2bs(v[0]), f2bs(v[1]), f2bs(v[2]), f2bs(v[3])};
    *(short4v*)((short*)xb + base) = s;
  } else if (base < NX + NIW) {
    const int off = base - NX;
    f32x4 v = *(const f32x4*)(in_w + off);
    short4v s = {f2bs(v[0]), f2bs(v[1]), f2bs(v[2]), f2bs(v[3])};
    *(short4v*)((short*)wb_in + off) = s;
  } else if (base < NX + NIW + NXP) {
    const int off = base - NX - NIW;
    short4v s;
    if (off < 33 * HD) {   // 8448 % 4 == 0, whole quad in-range
      f32x4 v = *(const f32x4*)(xp_w + off);
      s = short4v{f2bs(v[0]), f2bs(v[1]), f2bs(v[2]), f2bs(v[3])};
    } else {
      s = short4v{0, 0, 0, 0};
    }
    *(short4v*)((short*)wb_xp + off) = s;
  } else if (base < NX + NIW + NXP + NOW) {
    const int off = base - NX - NIW - NXP;
    f32x4 v = *(const f32x4*)(out_w + off);
    short4v s = {f2bs(v[0]), f2bs(v[1]), f2bs(v[2]), f2bs(v[3])};
    *(short4v*)((short*)wb_out + off) = s;
  }
}

// ---------------------------------------------------------------------------
// K1: xz[m, 0:512] = x[m,:] @ in_w^T + in_b  (bf16 MFMA, fp32 out)
// Block: 4 waves; tile 16 rows x 512 cols; wave = 128 cols.
// ---------------------------------------------------------------------------
__global__ __launch_bounds__(256) void k1_in_gemm(
    const bf16* __restrict__ xb, const bf16* __restrict__ wb_in,
    const float* __restrict__ in_b, float* __restrict__ xz)
{
  const int mb = blockIdx.x * 16;
  const int wave = threadIdx.x >> 6;
  const int lane = threadIdx.x & 63;
  const int q = lane >> 4;        // quad
  const int l16 = lane & 15;
  const int colBase = wave * 128;

  f32x4 acc[8] = {};
  const bf16* aptr = xb + (size_t)(mb + l16) * HD + q * 8;       // A[m][k]
  const bf16* bptr = wb_in + (size_t)(colBase + l16) * HD + q * 8; // B[k][n]=W[n][k]
  for (int k = 0; k < HD; k += 32) {
    bf16x8 af = *(const bf16x8*)(aptr + k);
#pragma unroll
    for (int t = 0; t < 8; ++t) {
      bf16x8 bfr = *(const bf16x8*)(bptr + (size_t)t * 16 * HD + k);
      acc[t] = __builtin_amdgcn_mfma_f32_16x16x32_bf16(af, bfr, acc[t], 0, 0, 0);
    }
  }
  // C/D: col = lane&15, row = quad*4 + reg
#pragma unroll
  for (int t = 0; t < 8; ++t) {
    const int col = colBase + t * 16 + l16;
    const float bias = in_b[col];
#pragma unroll
    for (int r = 0; r < 4; ++r) {
      const int row = mb + q * 4 + r;
      xz[(size_t)row * 512 + col] = acc[t][r] + bias;
    }
  }
}

// ---------------------------------------------------------------------------
// K2: dbc[m, 0:33] = x_inner[m,:] @ xp_w^T + xp_b  (N padded 33->48)
// A operand: fp32 xz cols 0:256 converted to bf16 in-register.
// ---------------------------------------------------------------------------
__global__ __launch_bounds__(256) void k2_xp_gemm(
    const float* __restrict__ xz, const bf16* __restrict__ wb_xp,
    const float* __restrict__ xp_b, float* __restrict__ dbc)
{
  const int wave = threadIdx.x >> 6;
  const int lane = threadIdx.x & 63;
  const int q = lane >> 4;
  const int l16 = lane & 15;
  const int mb = blockIdx.x * 64 + wave * 16;

  f32x4 acc[3] = {};
  const float* aptr = xz + (size_t)(mb + l16) * 512 + q * 8;
  const bf16* bptr = wb_xp + (size_t)l16 * HD + q * 8;
  for (int k = 0; k < HD; k += 32) {
    bf16x8 af = cvt_frag(aptr + k);
#pragma unroll
    for (int t = 0; t < 3; ++t) {
      bf16x8 bfr = *(const bf16x8*)(bptr + (size_t)t * 16 * HD + k);
      acc[t] = __builtin_amdgcn_mfma_f32_16x16x32_bf16(af, bfr, acc[t], 0, 0, 0);
    }
  }
#pragma unroll
  for (int t = 0; t < 3; ++t) {
    const int col = t * 16 + l16;
    if (col < 33) {
      const float bias = xp_b[col];
#pragma unroll
      for (int r = 0; r < 4; ++r) {
        const int row = mb + q * 4 + r;
        dbc[(size_t)row * 33 + col] = acc[t][r] + bias;
      }
    }
  }
}

// ---------------------------------------------------------------------------
// K3: per-chunk state sums  Mc[b,c,h,s] = sum_{n in chunk} u[n,h]*B[n,s]
// ---------------------------------------------------------------------------
__global__ __launch_bounds__(256) void k3_chunksum(
    const float* __restrict__ xz, const float* __restrict__ dbc,
    const float* __restrict__ dt_w, const float* __restrict__ dt_b,
    float* __restrict__ Mc)
{
  const int blk = blockIdx.x;
  const int b = blk / NCHUNK, c = blk % NCHUNK;
  const int h = threadIdx.x;
  const int rowBase = b * NSEQ + c * CHUNK;
  __shared__ float sdbc[CHUNK][17];   // dt_raw + B[16]
  for (int idx = threadIdx.x; idx < CHUNK * 17; idx += 256) {
    const int n = idx / 17, j = idx - n * 17;
    sdbc[n][j] = dbc[(size_t)(rowBase + n) * 33 + j];
  }
  __syncthreads();
  const float dtw = dt_w[h];
  const float dtb = dt_b[h];
  float st[SD] = {};
  for (int n = 0; n < CHUNK; ++n) {
    const float xv = xz[(size_t)(rowBase + n) * 512 + h];
    const float a = sdbc[n][0] * dtw + dtb;
    const float dt = (a > 20.f) ? a : log1pf(__expf(a));  // softplus
    const float u = xv * dt;
#pragma unroll
    for (int s = 0; s < SD; ++s) st[s] += u * sdbc[n][1 + s];
  }
  float* outp = Mc + (size_t)blk * HD * SD + h * SD;
#pragma unroll
  for (int s = 0; s < SD; ++s) outp[s] = st[s];
}

// ---------------------------------------------------------------------------
// K4a: exclusive prefix of Mc within each group of GSZ chunks (in-place);
// group totals -> Gs[b][g][hs].
// ---------------------------------------------------------------------------
__global__ __launch_bounds__(256) void k4a_prefix_local(
    float* __restrict__ Mc, float* __restrict__ Gs)
{
  const int tid = blockIdx.x * 256 + threadIdx.x;   // 131072 threads
  const int b = tid >> 16;
  const int g = (tid >> 12) & (NGRP - 1);
  const int hs = tid & 4095;
  float run = 0.f;
#pragma unroll
  for (int i = 0; i < GSZ; ++i) {
    const size_t idx = ((size_t)(b * NCHUNK + g * GSZ + i)) * 4096 + hs;
    const float v = Mc[idx];
    Mc[idx] = run;
    run += v;
  }
  Gs[((size_t)(b * NGRP + g)) * 4096 + hs] = run;
}

// ---------------------------------------------------------------------------
// K4b: exclusive prefix over the NGRP group totals (in-place).
// ---------------------------------------------------------------------------
__global__ __launch_bounds__(256) void k4b_prefix_groups(float* __restrict__ Gs)
{
  const int tid = blockIdx.x * 256 + threadIdx.x;   // 8192 threads
  const int b = tid >> 12;
  const int hs = tid & 4095;
  float run = 0.f;
#pragma unroll
  for (int g = 0; g < NGRP; ++g) {
    const size_t idx = ((size_t)(b * NGRP + g)) * 4096 + hs;
    const float v = Gs[idx];
    Gs[idx] = run;
    run += v;
  }
}

// ---------------------------------------------------------------------------
// K5: seeded local scan -> y = C.h + D*x_inner, gated by silu(z), bf16 out.
// ---------------------------------------------------------------------------
__global__ __launch_bounds__(256) void k5_scan(
    const float* __restrict__ xz, const float* __restrict__ dbc,
    const float* __restrict__ dt_w, const float* __restrict__ dt_b,
    const float* __restrict__ Dv, const float* __restrict__ Mc,
    const float* __restrict__ Gs, bf16* __restrict__ yg)
{
  const int blk = blockIdx.x;
  const int b = blk / NCHUNK, c = blk % NCHUNK;
  const int h = threadIdx.x;
  const int rowBase = b * NSEQ + c * CHUNK;
  __shared__ float sdbc[CHUNK][33];   // dt_raw, B[16], C[16]
  for (int idx = threadIdx.x; idx < CHUNK * 33; idx += 256) {
    const int n = idx / 33, j = idx - n * 33;
    sdbc[n][j] = dbc[(size_t)(rowBase + n) * 33 + j];
  }
  __syncthreads();
  const float dtw = dt_w[h];
  const float dtb = dt_b[h];
  const float dv = Dv[h];
  float st[SD];
  const float* mp = Mc + (size_t)blk * 4096 + h * SD;
  const float* gp = Gs + ((size_t)(b * NGRP + (c / GSZ))) * 4096 + h * SD;
#pragma unroll
  for (int s = 0; s < SD; ++s) st[s] = mp[s] + gp[s];
  for (int n = 0; n < CHUNK; ++n) {
    const int row = rowBase + n;
    const float xv = xz[(size_t)row * 512 + h];
    const float zv = xz[(size_t)row * 512 + HD + h];
    const float a = sdbc[n][0] * dtw + dtb;
    const float dt = (a > 20.f) ? a : log1pf(__expf(a));
    const float u = xv * dt;
    float y = dv * xv;
#pragma unroll
    for (int s = 0; s < SD; ++s) {
      st[s] += u * sdbc[n][1 + s];
      y += st[s] * sdbc[n][17 + s];
    }
    const float sig = 1.f / (1.f + __expf(-zv));
    y *= zv * sig;
    yg[(size_t)row * HD + h] = __float2bfloat16(y);
  }
}

// ---------------------------------------------------------------------------
// K6: out = yg @ out_w^T + out_b + x (residual), then LayerNorm. fp32 out.
// ---------------------------------------------------------------------------
__global__ __launch_bounds__(256) void k6_out_ln(
    const bf16* __restrict__ yg, const bf16* __restrict__ wb_out,
    const float* __restrict__ out_b, const float* __restrict__ x,
    const float* __restrict__ ln_g, const float* __restrict__ ln_b,
    float* __restrict__ out)
{
  __shared__ float tile[16][260];   // +4 pad
  const int mb = blockIdx.x * 16;
  const int wave = threadIdx.x >> 6;
  const int lane = threadIdx.x & 63;
  const int q = lane >> 4;
  const int l16 = lane & 15;
  const int colBase = wave * 64;

  f32x4 acc[4] = {};
  const bf16* aptr = yg + (size_t)(mb + l16) * HD + q * 8;
  const bf16* bptr = wb_out + (size_t)(colBase + l16) * HD + q * 8;
  for (int k = 0; k < HD; k += 32) {
    bf16x8 af = *(const bf16x8*)(aptr + k);
#pragma unroll
    for (int t = 0; t < 4; ++t) {
      bf16x8 bfr = *(const bf16x8*)(bptr + (size_t)t * 16 * HD + k);
      acc[t] = __builtin_amdgcn_mfma_f32_16x16x32_bf16(af, bfr, acc[t], 0, 0, 0);
    }
  }
#pragma unroll
  for (int t = 0; t < 4; ++t) {
    const int col = colBase + t * 16 + l16;
    const float bias = out_b[col];
#pragma unroll
    for (int r = 0; r < 4; ++r) {
      const int row = q * 4 + r;
      tile[row][col] = acc[t][r] + bias + x[(size_t)(mb + row) * HD + col];
    }
  }
  __syncthreads();
#pragma unroll
  for (int rr = 0; rr < 4; ++rr) {
    const int row = wave * 4 + rr;
    float p = 0.f;
#pragma unroll
    for (int j = 0; j < 4; ++j) p += tile[row][lane + 64 * j];
#pragma unroll
    for (int off = 32; off > 0; off >>= 1) p += __shfl_xor(p, off);
    const float mu = p * (1.f / 256.f);
    float v2 = 0.f;
#pragma unroll
    for (int j = 0; j < 4; ++j) { const float d = tile[row][lane + 64 * j] - mu; v2 += d * d; }
#pragma unroll
    for (int off = 32; off > 0; off >>= 1) v2 += __shfl_xor(v2, off);
    const float rstd = rsqrtf(v2 * (1.f / 256.f) + LN_EPS);
    const size_t base = (size_t)(mb + row) * HD;
#pragma unroll
    for (int j = 0; j < 4; ++j) {
      const int cc = lane + 64 * j;
      out[base + cc] = ln_g[cc] * (tile[row][cc] - mu) * rstd + ln_b[cc];
    }
  }
}

// ---------------------------------------------------------------------------
extern "C" void kernel_launch(void* const* d_in, const int* in_sizes, int n_in,
                              void* d_out, int out_size, void* d_ws, size_t ws_size,
                              hipStream_t stream)
{
  const float* x     = (const float*)d_in[0];
  const float* in_w  = (const float*)d_in[1];
  const float* in_b  = (const float*)d_in[2];
  const float* xp_w  = (const float*)d_in[3];
  const float* xp_b  = (const float*)d_in[4];
  const float* dt_w  = (const float*)d_in[5];
  const float* dt_b  = (const float*)d_in[6];
  // d_in[7] = A_log — unused by the reference computation
  const float* Dv    = (const float*)d_in[8];
  const float* out_w = (const float*)d_in[9];
  const float* out_b = (const float*)d_in[10];
  const float* ln_g  = (const float*)d_in[11];
  const float* ln_b  = (const float*)d_in[12];

  char* ws = (char*)d_ws;
  float* xz    = (float*)(ws);              // BN*512 f32     = 33,554,432 B
  float* dbc   = (float*)(ws + 33554432);   // BN*33 f32      =  2,162,688 B
  float* Mc    = (float*)(ws + 35717120);   // 2*256*4096 f32 =  8,388,608 B
  float* Gs    = (float*)(ws + 44105728);   // 2*16*4096 f32  =    524,288 B
  bf16*  yg    = (bf16*)(ws + 44630016);    // BN*256 bf16    =  8,388,608 B
  bf16*  xb    = (bf16*)(ws + 53018624);    // BN*256 bf16    =  8,388,608 B
  bf16*  wbin  = (bf16*)(ws + 61407232);    // 512*256 bf16   =    262,144 B
  bf16*  wbxp  = (bf16*)(ws + 61669376);    // 48*256 bf16    =     24,576 B
  bf16*  wbout = (bf16*)(ws + 61693952);    // 256*256 bf16   =    131,072 B
  float* out   = (float*)d_out;

  hipLaunchKernelGGL(k0_convert, dim3((NX + NIW + NXP + NOW) / 1024), dim3(256),
                     0, stream, x, in_w, xp_w, out_w, xb, wbin, wbxp, wbout);
  hipLaunchKernelGGL(k1_in_gemm, dim3(BN / 16), dim3(256), 0, stream,
                     xb, wbin, in_b, xz);
  hipLaunchKernelGGL(k2_xp_gemm, dim3(BN / 64), dim3(256), 0, stream,
                     xz, wbxp, xp_b, dbc);
  hipLaunchKernelGGL(k3_chunksum, dim3(NBATCH * NCHUNK), dim3(256), 0, stream,
                     xz, dbc, dt_w, dt_b, Mc);
  hipLaunchKernelGGL(k4a_prefix_local, dim3(NBATCH * NGRP * 4096 / 256), dim3(256),
                     0, stream, Mc, Gs);
  hipLaunchKernelGGL(k4b_prefix_groups, dim3(NBATCH * 4096 / 256), dim3(256),
                     0, stream, Gs);
  hipLaunchKernelGGL(k5_scan, dim3(NBATCH * NCHUNK), dim3(256), 0, stream,
                     xz, dbc, dt_w, dt_b, Dv, Mc, Gs, yg);
  hipLaunchKernelGGL(k6_out_ln, dim3(BN / 16), dim3(256), 0, stream,
                     yg, wbout, out_b, x, ln_g, ln_b, out);
}

// Round 3
// 185.554 us; speedup vs baseline: 1.1392x; 1.1392x over previous
//
#include <hip/hip_runtime.h>
#include <hip/hip_bf16.h>

// MambaBlock: H=256, S=16, B=2, N=8192. fp32 I/O.
// No decay (A_log unused) => SSM state is a pure prefix-sum: chunk-parallel.
// Round 3: bf16 intermediates (xib/zb), fused k2+k3 and k5+k6, LDS-staged
// coalesced epilogues. 6 kernels.

#define HD 256
#define SD 16
#define NSEQ 8192
#define NBATCH 2
#define BN (NBATCH * NSEQ)      // 16384 rows
#define CHUNK 32
#define NCHUNK (NSEQ / CHUNK)   // 256
#define NGRP 16
#define GSZ (NCHUNK / NGRP)     // 16
#define LN_EPS 1e-5f

#define NIW (2 * HD * HD)       // 131,072 in_w
#define NXP (48 * HD)           // 12,288  xp_w padded (src 33*256=8448)
#define NOW (HD * HD)           // 65,536  out_w

typedef __hip_bfloat16 bf16;
typedef __attribute__((ext_vector_type(8))) short bf16x8;
typedef __attribute__((ext_vector_type(4))) short short4v;
typedef __attribute__((ext_vector_type(4))) float f32x4;

__device__ __forceinline__ float b2f(bf16 v) { return __bfloat162float(v); }
__device__ __forceinline__ short f2bs(float f) {
  union { bf16 b; short s; } u;
  u.b = __float2bfloat16(f);
  return u.s;
}
__device__ __forceinline__ bf16x8 cvt_frag(const float* p) {
  bf16x8 r;
#pragma unroll
  for (int j = 0; j < 8; ++j) r[j] = f2bs(p[j]);
  return r;
}
__device__ __forceinline__ float softplus_f(float a) {
  return (a > 20.f) ? a : __logf(1.f + __expf(a));
}

// ---------------------------------------------------------------------------
// K0: weight conversions fp32->bf16 (xp_w zero-padded 33->48 rows).
// ---------------------------------------------------------------------------
__global__ __launch_bounds__(256) void k0_weights(
    const float* __restrict__ in_w, const float* __restrict__ xp_w,
    const float* __restrict__ out_w, bf16* __restrict__ wbin,
    bf16* __restrict__ wbxp, bf16* __restrict__ wbout)
{
  const int base = (blockIdx.x * 256 + threadIdx.x) * 4;
  if (base < NIW) {
    f32x4 v = *(const f32x4*)(in_w + base);
    *(short4v*)((short*)wbin + base) =
        short4v{f2bs(v[0]), f2bs(v[1]), f2bs(v[2]), f2bs(v[3])};
  } else if (base < NIW + NXP) {
    const int off = base - NIW;
    short4v s;
    if (off < 33 * HD) {
      f32x4 v = *(const f32x4*)(xp_w + off);
      s = short4v{f2bs(v[0]), f2bs(v[1]), f2bs(v[2]), f2bs(v[3])};
    } else {
      s = short4v{0, 0, 0, 0};
    }
    *(short4v*)((short*)wbxp + off) = s;
  } else if (base < NIW + NXP + NOW) {
    const int off = base - NIW - NXP;
    f32x4 v = *(const f32x4*)(out_w + off);
    *(short4v*)((short*)wbout + off) =
        short4v{f2bs(v[0]), f2bs(v[1]), f2bs(v[2]), f2bs(v[3])};
  }
}

// ---------------------------------------------------------------------------
// K1: [x_inner | z] = x @ in_w^T + in_b ; bf16 outputs via LDS-staged
// coalesced stores. Block: 4 waves, tile 16 rows x 512 cols.
// ---------------------------------------------------------------------------
__global__ __launch_bounds__(256) void k1_in_gemm(
    const float* __restrict__ x, const bf16* __restrict__ wbin,
    const float* __restrict__ in_b, bf16* __restrict__ xib,
    bf16* __restrict__ zb)
{
  __shared__ float tile[16][520];   // stride%32==8 -> 2-way on C-write (free)
  const int mb = blockIdx.x * 16;
  const int wave = threadIdx.x >> 6;
  const int lane = threadIdx.x & 63;
  const int q = lane >> 4;
  const int l16 = lane & 15;
  const int colBase = wave * 128;

  f32x4 acc[8] = {};
  const float* aptr = x + (size_t)(mb + l16) * HD + q * 8;
  const bf16* bptr = wbin + (size_t)(colBase + l16) * HD + q * 8;
  for (int k = 0; k < HD; k += 32) {
    bf16x8 af = cvt_frag(aptr + k);
#pragma unroll
    for (int t = 0; t < 8; ++t) {
      bf16x8 bfr = *(const bf16x8*)(bptr + (size_t)t * 16 * HD + k);
      acc[t] = __builtin_amdgcn_mfma_f32_16x16x32_bf16(af, bfr, acc[t], 0, 0, 0);
    }
  }
  // C/D: col = lane&15, row = quad*4 + reg
#pragma unroll
  for (int t = 0; t < 8; ++t) {
    const int col = colBase + t * 16 + l16;
    const float bias = in_b[col];
#pragma unroll
    for (int r = 0; r < 4; ++r) tile[q * 4 + r][col] = acc[t][r] + bias;
  }
  __syncthreads();
  // coalesced bf16 stores: thread -> (row, 8-col group) x 4 stores
  const int row = threadIdx.x >> 4;
  const int g = threadIdx.x & 15;
#pragma unroll
  for (int j = 0; j < 4; ++j) {
    const int c8 = j * 128 + g * 8;          // 0..511
    bf16x8 v = cvt_frag(&tile[row][c8]);
    bf16* dst = (c8 < 256) ? (xib + (size_t)(mb + row) * HD + c8)
                           : (zb + (size_t)(mb + row) * HD + (c8 - 256));
    *(bf16x8*)dst = v;
  }
}

// ---------------------------------------------------------------------------
// K23: dbc = x_inner @ xp_w^T + xp_b (GEMM) fused with per-chunk state sums
// Mc[b,c,h,s]. Block: 64 rows = 2 chunks, 4 waves x 16 rows for the GEMM.
// ---------------------------------------------------------------------------
__global__ __launch_bounds__(256) void k23_xp_chunksum(
    const bf16* __restrict__ xib, const bf16* __restrict__ wbxp,
    const float* __restrict__ xp_b, const float* __restrict__ dt_w,
    const float* __restrict__ dt_b, float* __restrict__ dbc,
    float* __restrict__ Mc)
{
  __shared__ float sdbc[64][33];
  const int wave = threadIdx.x >> 6;
  const int lane = threadIdx.x & 63;
  const int q = lane >> 4;
  const int l16 = lane & 15;
  const int R0 = blockIdx.x * 64;
  const int mb = R0 + wave * 16;

  f32x4 acc[3] = {};
  const bf16* aptr = xib + (size_t)(mb + l16) * HD + q * 8;
  const bf16* bptr = wbxp + (size_t)l16 * HD + q * 8;
  for (int k = 0; k < HD; k += 32) {
    bf16x8 af = *(const bf16x8*)(aptr + k);
#pragma unroll
    for (int t = 0; t < 3; ++t) {
      bf16x8 bfr = *(const bf16x8*)(bptr + (size_t)t * 16 * HD + k);
      acc[t] = __builtin_amdgcn_mfma_f32_16x16x32_bf16(af, bfr, acc[t], 0, 0, 0);
    }
  }
#pragma unroll
  for (int t = 0; t < 3; ++t) {
    const int col = t * 16 + l16;
    if (col < 33) {
      const float bias = xp_b[col];
#pragma unroll
      for (int r = 0; r < 4; ++r) {
        const int lrow = wave * 16 + q * 4 + r;
        const float v = acc[t][r] + bias;
        sdbc[lrow][col] = v;
        dbc[(size_t)(R0 + lrow) * 33 + col] = v;
      }
    }
  }
  __syncthreads();
  // chunk sums: thread = channel h, 2 chunks of 32 rows
  const int h = threadIdx.x;
  const int b = R0 >> 13;
  const int c0 = (R0 & (NSEQ - 1)) >> 5;
  const float dtw = dt_w[h];
  const float dtb = dt_b[h];
#pragma unroll
  for (int c2 = 0; c2 < 2; ++c2) {
    float st[SD] = {};
    for (int n = 0; n < CHUNK; ++n) {
      const int ln = c2 * CHUNK + n;
      const float xv = b2f(xib[(size_t)(R0 + ln) * HD + h]);
      const float dt = softplus_f(sdbc[ln][0] * dtw + dtb);
      const float u = xv * dt;
#pragma unroll
      for (int s = 0; s < SD; ++s) st[s] += u * sdbc[ln][1 + s];
    }
    float* outp = Mc + ((size_t)(b * NCHUNK + c0 + c2)) * (HD * SD) + h * SD;
#pragma unroll
    for (int s = 0; s < SD; ++s) outp[s] = st[s];
  }
}

// ---------------------------------------------------------------------------
// K4a: exclusive prefix of Mc within each group of GSZ chunks (in-place);
// group totals -> Gs.
// ---------------------------------------------------------------------------
__global__ __launch_bounds__(256) void k4a_prefix_local(
    float* __restrict__ Mc, float* __restrict__ Gs)
{
  const int tid = blockIdx.x * 256 + threadIdx.x;   // 131072
  const int b = tid >> 16;
  const int g = (tid >> 12) & (NGRP - 1);
  const int hs = tid & 4095;
  float run = 0.f;
#pragma unroll
  for (int i = 0; i < GSZ; ++i) {
    const size_t idx = ((size_t)(b * NCHUNK + g * GSZ + i)) * 4096 + hs;
    const float v = Mc[idx];
    Mc[idx] = run;
    run += v;
  }
  Gs[((size_t)(b * NGRP + g)) * 4096 + hs] = run;
}

// ---------------------------------------------------------------------------
// K4b: exclusive prefix over the NGRP group totals (in-place).
// ---------------------------------------------------------------------------
__global__ __launch_bounds__(256) void k4b_prefix_groups(float* __restrict__ Gs)
{
  const int tid = blockIdx.x * 256 + threadIdx.x;   // 8192
  const int b = tid >> 12;
  const int hs = tid & 4095;
  float run = 0.f;
#pragma unroll
  for (int g = 0; g < NGRP; ++g) {
    const size_t idx = ((size_t)(b * NGRP + g)) * 4096 + hs;
    const float v = Gs[idx];
    Gs[idx] = run;
    run += v;
  }
}

// ---------------------------------------------------------------------------
// K56: seeded scan -> y (fp32, LDS) -> out GEMM (y @ out_w^T + out_b)
//      + residual + LayerNorm. Block = 1 chunk (32 rows), 4 waves.
// ---------------------------------------------------------------------------
__global__ __launch_bounds__(256) void k56_scan_out_ln(
    const bf16* __restrict__ xib, const bf16* __restrict__ zb,
    const float* __restrict__ dbc, const float* __restrict__ dt_w,
    const float* __restrict__ dt_b, const float* __restrict__ Dv,
    const float* __restrict__ Mc, const float* __restrict__ Gs,
    const bf16* __restrict__ wbout, const float* __restrict__ out_b,
    const float* __restrict__ x, const float* __restrict__ ln_g,
    const float* __restrict__ ln_b, float* __restrict__ out)
{
  __shared__ float sdbc[CHUNK][33];    // 4.2 KB
  __shared__ float ytile[32][264];     // 33.8 KB, stride%32==8
  const int tid = threadIdx.x;
  const int R0 = blockIdx.x * CHUNK;
  const int b = R0 >> 13;
  const int cchunk = (R0 & (NSEQ - 1)) >> 5;

  for (int idx = tid; idx < CHUNK * 33; idx += 256) {
    const int n = idx / 33, j = idx - n * 33;
    sdbc[n][j] = dbc[(size_t)(R0 + n) * 33 + j];
  }
  __syncthreads();

  // ---- scan: thread = channel h ----
  {
    const int h = tid;
    const float dtw = dt_w[h];
    const float dtb = dt_b[h];
    const float dv = Dv[h];
    float st[SD];
    const float* mp = Mc + ((size_t)(b * NCHUNK + cchunk)) * 4096 + h * SD;
    const float* gp = Gs + ((size_t)(b * NGRP + cchunk / GSZ)) * 4096 + h * SD;
#pragma unroll
    for (int s = 0; s < SD; ++s) st[s] = mp[s] + gp[s];
    for (int n = 0; n < CHUNK; ++n) {
      const size_t row = (size_t)(R0 + n) * HD + h;
      const float xv = b2f(xib[row]);
      const float zv = b2f(zb[row]);
      const float dt = softplus_f(sdbc[n][0] * dtw + dtb);
      const float u = xv * dt;
      float y = dv * xv;
#pragma unroll
      for (int s = 0; s < SD; ++s) {
        st[s] += u * sdbc[n][1 + s];
        y += st[s] * sdbc[n][17 + s];
      }
      const float sig = 1.f / (1.f + __expf(-zv));
      ytile[n][h] = y * zv * sig;
    }
  }
  __syncthreads();

  // ---- out GEMM from LDS A ----
  const int wave = tid >> 6;
  const int lane = tid & 63;
  const int q = lane >> 4;
  const int l16 = lane & 15;
  const int mrow = (wave & 1) * 16;
  const int colBase = (wave >> 1) * 128;

  f32x4 acc[8] = {};
  const bf16* bptr = wbout + (size_t)(colBase + l16) * HD + q * 8;
  for (int k = 0; k < HD; k += 32) {
    bf16x8 af = cvt_frag(&ytile[mrow + l16][k + q * 8]);
#pragma unroll
    for (int t = 0; t < 8; ++t) {
      bf16x8 bfr = *(const bf16x8*)(bptr + (size_t)t * 16 * HD + k);
      acc[t] = __builtin_amdgcn_mfma_f32_16x16x32_bf16(af, bfr, acc[t], 0, 0, 0);
    }
  }
  __syncthreads();   // all ytile reads done before overwrite

  // r = acc + out_b + residual -> back into ytile
#pragma unroll
  for (int t = 0; t < 8; ++t) {
    const int col = colBase + t * 16 + l16;
    const float bias = out_b[col];
#pragma unroll
    for (int r = 0; r < 4; ++r) {
      const int row = mrow + q * 4 + r;
      ytile[row][col] = acc[t][r] + bias + x[(size_t)(R0 + row) * HD + col];
    }
  }
  __syncthreads();

  // ---- LayerNorm: wave handles rows wave*8 .. wave*8+7 ----
#pragma unroll
  for (int rr = 0; rr < 8; ++rr) {
    const int row = wave * 8 + rr;
    float p = 0.f;
#pragma unroll
    for (int j = 0; j < 4; ++j) p += ytile[row][lane + 64 * j];
#pragma unroll
    for (int off = 32; off > 0; off >>= 1) p += __shfl_xor(p, off);
    const float mu = p * (1.f / 256.f);
    float v2 = 0.f;
#pragma unroll
    for (int j = 0; j < 4; ++j) {
      const float d = ytile[row][lane + 64 * j] - mu;
      v2 += d * d;
    }
#pragma unroll
    for (int off = 32; off > 0; off >>= 1) v2 += __shfl_xor(v2, off);
    const float rstd = rsqrtf(v2 * (1.f / 256.f) + LN_EPS);
    const size_t base = (size_t)(R0 + row) * HD;
#pragma unroll
    for (int j = 0; j < 4; ++j) {
      const int cc = lane + 64 * j;
      out[base + cc] = ln_g[cc] * (ytile[row][cc] - mu) * rstd + ln_b[cc];
    }
  }
}

// ---------------------------------------------------------------------------
extern "C" void kernel_launch(void* const* d_in, const int* in_sizes, int n_in,
                              void* d_out, int out_size, void* d_ws, size_t ws_size,
                              hipStream_t stream)
{
  const float* x     = (const float*)d_in[0];
  const float* in_w  = (const float*)d_in[1];
  const float* in_b  = (const float*)d_in[2];
  const float* xp_w  = (const float*)d_in[3];
  const float* xp_b  = (const float*)d_in[4];
  const float* dt_w  = (const float*)d_in[5];
  const float* dt_b  = (const float*)d_in[6];
  // d_in[7] = A_log — unused by the reference
  const float* Dv    = (const float*)d_in[8];
  const float* out_w = (const float*)d_in[9];
  const float* out_b = (const float*)d_in[10];
  const float* ln_g  = (const float*)d_in[11];
  const float* ln_b  = (const float*)d_in[12];

  char* ws = (char*)d_ws;
  bf16*  xib   = (bf16*)(ws);               // 8,388,608 B
  bf16*  zb    = (bf16*)(ws +  8388608);    // 8,388,608 B
  float* dbc   = (float*)(ws + 16777216);   // 2,162,688 B
  float* Mc    = (float*)(ws + 18939904);   // 8,388,608 B
  float* Gs    = (float*)(ws + 27328512);   //   524,288 B
  bf16*  wbin  = (bf16*)(ws + 27852800);    //   262,144 B
  bf16*  wbxp  = (bf16*)(ws + 28114944);    //    24,576 B
  bf16*  wbout = (bf16*)(ws + 28139520);    //   131,072 B
  float* out   = (float*)d_out;

  hipLaunchKernelGGL(k0_weights, dim3((NIW + NXP + NOW) / 1024), dim3(256),
                     0, stream, in_w, xp_w, out_w, wbin, wbxp, wbout);
  hipLaunchKernelGGL(k1_in_gemm, dim3(BN / 16), dim3(256), 0, stream,
                     x, wbin, in_b, xib, zb);
  hipLaunchKernelGGL(k23_xp_chunksum, dim3(BN / 64), dim3(256), 0, stream,
                     xib, wbxp, xp_b, dt_w, dt_b, dbc, Mc);
  hipLaunchKernelGGL(k4a_prefix_local, dim3(NBATCH * NGRP * 4096 / 256),
                     dim3(256), 0, stream, Mc, Gs);
  hipLaunchKernelGGL(k4b_prefix_groups, dim3(NBATCH * 4096 / 256), dim3(256),
                     0, stream, Gs);
  hipLaunchKernelGGL(k56_scan_out_ln, dim3(BN / CHUNK), dim3(256), 0, stream,
                     xib, zb, dbc, dt_w, dt_b, Dv, Mc, Gs,
                     wbout, out_b, x, ln_g, ln_b, out);
}

// Round 4
// 167.504 us; speedup vs baseline: 1.2619x; 1.1078x over previous
//
#include <hip/hip_runtime.h>
#include <hip/hip_bf16.h>

// MambaBlock: H=256, S=16, B=2, N=8192. fp32 I/O.
// No decay (A_log unused) => SSM state is a pure prefix-sum: chunk-parallel.
// Round 4: k1+k23 fused (in-GEMM + xp-GEMM + chunk-sum in one block over a
// 32-row chunk), unrolled k-loops for MLP, [s][h] Mc layout. 5 kernels.

#define HD 256
#define SD 16
#define NSEQ 8192
#define NBATCH 2
#define BN (NBATCH * NSEQ)      // 16384 rows
#define CHUNK 32
#define NCHUNK (NSEQ / CHUNK)   // 256
#define NGRP 16
#define GSZ (NCHUNK / NGRP)     // 16
#define LN_EPS 1e-5f

#define NIW (2 * HD * HD)       // 131,072 in_w
#define NXP (48 * HD)           // 12,288  xp_w padded (src 33*256=8448)
#define NOW (HD * HD)           // 65,536  out_w

typedef __hip_bfloat16 bf16;
typedef __attribute__((ext_vector_type(8))) short bf16x8;
typedef __attribute__((ext_vector_type(4))) short short4v;
typedef __attribute__((ext_vector_type(4))) float f32x4;

__device__ __forceinline__ float b2f(bf16 v) { return __bfloat162float(v); }
__device__ __forceinline__ short f2bs(float f) {
  union { bf16 b; short s; } u;
  u.b = __float2bfloat16(f);
  return u.s;
}
__device__ __forceinline__ bf16x8 cvt_frag(const float* p) {
  bf16x8 r;
#pragma unroll
  for (int j = 0; j < 8; ++j) r[j] = f2bs(p[j]);
  return r;
}
__device__ __forceinline__ float softplus_f(float a) {
  return (a > 20.f) ? a : __logf(1.f + __expf(a));
}

// ---------------------------------------------------------------------------
// K0: weight conversions fp32->bf16 (xp_w zero-padded 33->48 rows).
// ---------------------------------------------------------------------------
__global__ __launch_bounds__(256) void k0_weights(
    const float* __restrict__ in_w, const float* __restrict__ xp_w,
    const float* __restrict__ out_w, bf16* __restrict__ wbin,
    bf16* __restrict__ wbxp, bf16* __restrict__ wbout)
{
  const int base = (blockIdx.x * 256 + threadIdx.x) * 4;
  if (base < NIW) {
    f32x4 v = *(const f32x4*)(in_w + base);
    *(short4v*)((short*)wbin + base) =
        short4v{f2bs(v[0]), f2bs(v[1]), f2bs(v[2]), f2bs(v[3])};
  } else if (base < NIW + NXP) {
    const int off = base - NIW;
    short4v s;
    if (off < 33 * HD) {
      f32x4 v = *(const f32x4*)(xp_w + off);
      s = short4v{f2bs(v[0]), f2bs(v[1]), f2bs(v[2]), f2bs(v[3])};
    } else {
      s = short4v{0, 0, 0, 0};
    }
    *(short4v*)((short*)wbxp + off) = s;
  } else if (base < NIW + NXP + NOW) {
    const int off = base - NIW - NXP;
    f32x4 v = *(const f32x4*)(out_w + off);
    *(short4v*)((short*)wbout + off) =
        short4v{f2bs(v[0]), f2bs(v[1]), f2bs(v[2]), f2bs(v[3])};
  }
}

// ---------------------------------------------------------------------------
// K1F: per 32-row chunk:
//   [x_inner|z] = x @ in_w^T + in_b            (MFMA, unrolled)
//   dbc = x_inner @ xp_w^T + xp_b              (MFMA from LDS x_inner)
//   Mc[c][s][h] = sum_n u[n,h]*B[n,s]          (chunk-sum from LDS)
//   xib, zb bf16 out (coalesced vec8)
// Block: 4 waves; main GEMM wave tile 32 rows x 128 cols (acc[2][8]).
// ---------------------------------------------------------------------------
__global__ __launch_bounds__(256) void k1f_in_xp_sum(
    const float* __restrict__ x, const bf16* __restrict__ wbin,
    const float* __restrict__ in_b, const bf16* __restrict__ wbxp,
    const float* __restrict__ xp_b, const float* __restrict__ dt_w,
    const float* __restrict__ dt_b, bf16* __restrict__ xib,
    bf16* __restrict__ zb, float* __restrict__ dbc, float* __restrict__ Mc)
{
  __shared__ float tile[32][260];   // 33.3 KB; 260%32==4 -> 2-way (free)
  __shared__ float sdbc[32][33];    // 4.2 KB; flat layout == dbc rows
  const int tid = threadIdx.x;
  const int wave = tid >> 6, lane = tid & 63, q = lane >> 4, l16 = lane & 15;
  const int R0 = blockIdx.x * CHUNK;

  // ---- main GEMM ----
  f32x4 acc[2][8] = {};
  {
    const float* a0 = x + (size_t)(R0 + l16) * HD + q * 8;
    const float* a1 = a0 + 16 * HD;
    const bf16* bp = wbin + (size_t)(wave * 128 + l16) * HD + q * 8;
#pragma unroll
    for (int k = 0; k < HD; k += 32) {
      bf16x8 af0 = cvt_frag(a0 + k);
      bf16x8 af1 = cvt_frag(a1 + k);
#pragma unroll
      for (int t = 0; t < 8; ++t) {
        bf16x8 bfr = *(const bf16x8*)(bp + (size_t)t * 16 * HD + k);
        acc[0][t] = __builtin_amdgcn_mfma_f32_16x16x32_bf16(af0, bfr, acc[0][t], 0, 0, 0);
        acc[1][t] = __builtin_amdgcn_mfma_f32_16x16x32_bf16(af1, bfr, acc[1][t], 0, 0, 0);
      }
    }
  }
  // ---- x_inner (cols 0..255) -> LDS fp32 (waves 0,1) ----
  if (wave < 2) {
#pragma unroll
    for (int t = 0; t < 8; ++t) {
      const int col = wave * 128 + t * 16 + l16;
      const float bias = in_b[col];
#pragma unroll
      for (int rt = 0; rt < 2; ++rt)
#pragma unroll
        for (int r = 0; r < 4; ++r)
          tile[rt * 16 + q * 4 + r][col] = acc[rt][t][r] + bias;
    }
  }
  __syncthreads();

  // ---- xib copy out (all threads) + xp-GEMM (waves 0,1) ----
  {
    const int row = tid >> 3;
    const int cb = (tid & 7) * 8;
#pragma unroll
    for (int j = 0; j < 4; ++j) {
      bf16x8 v = cvt_frag(&tile[row][cb + j * 64]);
      *(bf16x8*)(xib + (size_t)(R0 + row) * HD + cb + j * 64) = v;
    }
  }
  f32x4 pacc[3] = {};
  if (wave < 2) {
    const bf16* pb = wbxp + (size_t)l16 * HD + q * 8;
#pragma unroll
    for (int k = 0; k < HD; k += 32) {
      bf16x8 af = cvt_frag(&tile[wave * 16 + l16][k + q * 8]);
#pragma unroll
      for (int t = 0; t < 3; ++t) {
        bf16x8 bfr = *(const bf16x8*)(pb + (size_t)t * 16 * HD + k);
        pacc[t] = __builtin_amdgcn_mfma_f32_16x16x32_bf16(af, bfr, pacc[t], 0, 0, 0);
      }
    }
    // epilogue -> sdbc
#pragma unroll
    for (int t = 0; t < 3; ++t) {
      const int col = t * 16 + l16;
      if (col < 33) {
        const float bias = xp_b[col];
#pragma unroll
        for (int r = 0; r < 4; ++r)
          sdbc[wave * 16 + q * 4 + r][col] = pacc[t][r] + bias;
      }
    }
  }
  __syncthreads();

  // ---- dbc coalesced copy (sdbc flat == dbc rows) + chunk-sum ----
  {
    const float* sflat = &sdbc[0][0];
    for (int idx = tid; idx < CHUNK * 33; idx += 256)
      dbc[(size_t)R0 * 33 + idx] = sflat[idx];
  }
  {
    const int h = tid;
    const float dtw = dt_w[h], dtb = dt_b[h];
    float st[SD] = {};
#pragma unroll
    for (int n = 0; n < CHUNK; ++n) {
      const float xv = tile[n][h];
      const float dt = softplus_f(sdbc[n][0] * dtw + dtb);
      const float u = xv * dt;
#pragma unroll
      for (int s = 0; s < SD; ++s) st[s] += u * sdbc[n][1 + s];
    }
    const int b = R0 >> 13, c = (R0 & (NSEQ - 1)) >> 5;
    float* mp = Mc + ((size_t)(b * NCHUNK + c)) * 4096 + h;   // [s][h]
#pragma unroll
    for (int s = 0; s < SD; ++s) mp[s * HD] = st[s];
  }
  __syncthreads();

  // ---- z (cols 256..511) -> LDS (waves 2,3), then zb copy out ----
  if (wave >= 2) {
#pragma unroll
    for (int t = 0; t < 8; ++t) {
      const int gcol = wave * 128 + t * 16 + l16;
      const float bias = in_b[gcol];
      const int col = gcol - 256;
#pragma unroll
      for (int rt = 0; rt < 2; ++rt)
#pragma unroll
        for (int r = 0; r < 4; ++r)
          tile[rt * 16 + q * 4 + r][col] = acc[rt][t][r] + bias;
    }
  }
  __syncthreads();
  {
    const int row = tid >> 3;
    const int cb = (tid & 7) * 8;
#pragma unroll
    for (int j = 0; j < 4; ++j) {
      bf16x8 v = cvt_frag(&tile[row][cb + j * 64]);
      *(bf16x8*)(zb + (size_t)(R0 + row) * HD + cb + j * 64) = v;
    }
  }
}

// ---------------------------------------------------------------------------
// K4a: exclusive prefix of Mc within each group of GSZ chunks (in-place);
// group totals -> Gs. Flat over the 4096 hs slots per chunk.
// ---------------------------------------------------------------------------
__global__ __launch_bounds__(256) void k4a_prefix_local(
    float* __restrict__ Mc, float* __restrict__ Gs)
{
  const int tid = blockIdx.x * 256 + threadIdx.x;   // 131072
  const int b = tid >> 16;
  const int g = (tid >> 12) & (NGRP - 1);
  const int hs = tid & 4095;
  float run = 0.f;
#pragma unroll
  for (int i = 0; i < GSZ; ++i) {
    const size_t idx = ((size_t)(b * NCHUNK + g * GSZ + i)) * 4096 + hs;
    const float v = Mc[idx];
    Mc[idx] = run;
    run += v;
  }
  Gs[((size_t)(b * NGRP + g)) * 4096 + hs] = run;
}

// ---------------------------------------------------------------------------
// K4b: exclusive prefix over the NGRP group totals (in-place).
// ---------------------------------------------------------------------------
__global__ __launch_bounds__(256) void k4b_prefix_groups(float* __restrict__ Gs)
{
  const int tid = blockIdx.x * 256 + threadIdx.x;   // 8192
  const int b = tid >> 12;
  const int hs = tid & 4095;
  float run = 0.f;
#pragma unroll
  for (int g = 0; g < NGRP; ++g) {
    const size_t idx = ((size_t)(b * NGRP + g)) * 4096 + hs;
    const float v = Gs[idx];
    Gs[idx] = run;
    run += v;
  }
}

// ---------------------------------------------------------------------------
// K56: seeded scan -> y (fp32, LDS) -> out GEMM (y @ out_w^T + out_b)
//      + residual + LayerNorm. Block = 1 chunk (32 rows), 4 waves.
// ---------------------------------------------------------------------------
__global__ __launch_bounds__(256) void k56_scan_out_ln(
    const bf16* __restrict__ xib, const bf16* __restrict__ zb,
    const float* __restrict__ dbc, const float* __restrict__ dt_w,
    const float* __restrict__ dt_b, const float* __restrict__ Dv,
    const float* __restrict__ Mc, const float* __restrict__ Gs,
    const bf16* __restrict__ wbout, const float* __restrict__ out_b,
    const float* __restrict__ x, const float* __restrict__ ln_g,
    const float* __restrict__ ln_b, float* __restrict__ out)
{
  __shared__ float sdbc[CHUNK][33];    // 4.2 KB
  __shared__ float ytile[32][264];     // 33.8 KB
  const int tid = threadIdx.x;
  const int R0 = blockIdx.x * CHUNK;
  const int b = R0 >> 13;
  const int cchunk = (R0 & (NSEQ - 1)) >> 5;

  for (int idx = tid; idx < CHUNK * 33; idx += 256) {
    const int n = idx / 33, j = idx - n * 33;
    sdbc[n][j] = dbc[(size_t)(R0 + n) * 33 + j];
  }
  __syncthreads();

  // ---- scan: thread = channel h ----
  {
    const int h = tid;
    const float dtw = dt_w[h];
    const float dtb = dt_b[h];
    const float dv = Dv[h];
    float st[SD];
    const float* mp = Mc + ((size_t)(b * NCHUNK + cchunk)) * 4096 + h;  // [s][h]
    const float* gp = Gs + ((size_t)(b * NGRP + cchunk / GSZ)) * 4096 + h;
#pragma unroll
    for (int s = 0; s < SD; ++s) st[s] = mp[s * HD] + gp[s * HD];
    for (int n = 0; n < CHUNK; ++n) {
      const size_t row = (size_t)(R0 + n) * HD + h;
      const float xv = b2f(xib[row]);
      const float zv = b2f(zb[row]);
      const float dt = softplus_f(sdbc[n][0] * dtw + dtb);
      const float u = xv * dt;
      float y = dv * xv;
#pragma unroll
      for (int s = 0; s < SD; ++s) {
        st[s] += u * sdbc[n][1 + s];
        y += st[s] * sdbc[n][17 + s];
      }
      const float sig = 1.f / (1.f + __expf(-zv));
      ytile[n][h] = y * zv * sig;
    }
  }
  __syncthreads();

  // ---- out GEMM from LDS A ----
  const int wave = tid >> 6;
  const int lane = tid & 63;
  const int q = lane >> 4;
  const int l16 = lane & 15;
  const int mrow = (wave & 1) * 16;
  const int colBase = (wave >> 1) * 128;

  f32x4 acc[8] = {};
  const bf16* bptr = wbout + (size_t)(colBase + l16) * HD + q * 8;
#pragma unroll
  for (int k = 0; k < HD; k += 32) {
    bf16x8 af = cvt_frag(&ytile[mrow + l16][k + q * 8]);
#pragma unroll
    for (int t = 0; t < 8; ++t) {
      bf16x8 bfr = *(const bf16x8*)(bptr + (size_t)t * 16 * HD + k);
      acc[t] = __builtin_amdgcn_mfma_f32_16x16x32_bf16(af, bfr, acc[t], 0, 0, 0);
    }
  }
  __syncthreads();   // all ytile reads done before overwrite

  // r = acc + out_b + residual -> back into ytile
#pragma unroll
  for (int t = 0; t < 8; ++t) {
    const int col = colBase + t * 16 + l16;
    const float bias = out_b[col];
#pragma unroll
    for (int r = 0; r < 4; ++r) {
      const int row = mrow + q * 4 + r;
      ytile[row][col] = acc[t][r] + bias + x[(size_t)(R0 + row) * HD + col];
    }
  }
  __syncthreads();

  // ---- LayerNorm: wave handles rows wave*8 .. wave*8+7 ----
#pragma unroll
  for (int rr = 0; rr < 8; ++rr) {
    const int row = wave * 8 + rr;
    float p = 0.f;
#pragma unroll
    for (int j = 0; j < 4; ++j) p += ytile[row][lane + 64 * j];
#pragma unroll
    for (int off = 32; off > 0; off >>= 1) p += __shfl_xor(p, off);
    const float mu = p * (1.f / 256.f);
    float v2 = 0.f;
#pragma unroll
    for (int j = 0; j < 4; ++j) {
      const float d = ytile[row][lane + 64 * j] - mu;
      v2 += d * d;
    }
#pragma unroll
    for (int off = 32; off > 0; off >>= 1) v2 += __shfl_xor(v2, off);
    const float rstd = rsqrtf(v2 * (1.f / 256.f) + LN_EPS);
    const size_t base = (size_t)(R0 + row) * HD;
#pragma unroll
    for (int j = 0; j < 4; ++j) {
      const int cc = lane + 64 * j;
      out[base + cc] = ln_g[cc] * (ytile[row][cc] - mu) * rstd + ln_b[cc];
    }
  }
}

// ---------------------------------------------------------------------------
extern "C" void kernel_launch(void* const* d_in, const int* in_sizes, int n_in,
                              void* d_out, int out_size, void* d_ws, size_t ws_size,
                              hipStream_t stream)
{
  const float* x     = (const float*)d_in[0];
  const float* in_w  = (const float*)d_in[1];
  const float* in_b  = (const float*)d_in[2];
  const float* xp_w  = (const float*)d_in[3];
  const float* xp_b  = (const float*)d_in[4];
  const float* dt_w  = (const float*)d_in[5];
  const float* dt_b  = (const float*)d_in[6];
  // d_in[7] = A_log — unused by the reference
  const float* Dv    = (const float*)d_in[8];
  const float* out_w = (const float*)d_in[9];
  const float* out_b = (const float*)d_in[10];
  const float* ln_g  = (const float*)d_in[11];
  const float* ln_b  = (const float*)d_in[12];

  char* ws = (char*)d_ws;
  bf16*  xib   = (bf16*)(ws);               // 8,388,608 B
  bf16*  zb    = (bf16*)(ws +  8388608);    // 8,388,608 B
  float* dbc   = (float*)(ws + 16777216);   // 2,162,688 B
  float* Mc    = (float*)(ws + 18939904);   // 8,388,608 B
  float* Gs    = (float*)(ws + 27328512);   //   524,288 B
  bf16*  wbin  = (bf16*)(ws + 27852800);    //   262,144 B
  bf16*  wbxp  = (bf16*)(ws + 28114944);    //    24,576 B
  bf16*  wbout = (bf16*)(ws + 28139520);    //   131,072 B
  float* out   = (float*)d_out;

  hipLaunchKernelGGL(k0_weights, dim3((NIW + NXP + NOW) / 1024), dim3(256),
                     0, stream, in_w, xp_w, out_w, wbin, wbxp, wbout);
  hipLaunchKernelGGL(k1f_in_xp_sum, dim3(BN / CHUNK), dim3(256), 0, stream,
                     x, wbin, in_b, wbxp, xp_b, dt_w, dt_b,
                     xib, zb, dbc, Mc);
  hipLaunchKernelGGL(k4a_prefix_local, dim3(NBATCH * NGRP * 4096 / 256),
                     dim3(256), 0, stream, Mc, Gs);
  hipLaunchKernelGGL(k4b_prefix_groups, dim3(NBATCH * 4096 / 256), dim3(256),
                     0, stream, Gs);
  hipLaunchKernelGGL(k56_scan_out_ln, dim3(BN / CHUNK), dim3(256), 0, stream,
                     xib, zb, dbc, dt_w, dt_b, Dv, Mc, Gs,
                     wbout, out_b, x, ln_g, ln_b, out);
}